// Round 3
// baseline (133.283 us; speedup 1.0000x reference)
//
#include <hip/hip_runtime.h>
#include <hip/hip_bf16.h>

#define TGT   64
#define SRCN  64
#define BATCH 32
#define HID   512
#define ATT   512
#define MROWS (TGT * BATCH)          // 2048 rows per z

typedef __bf16 bf16_t;
typedef __bf16 bf16x8 __attribute__((ext_vector_type(8)));
typedef float  f32x4  __attribute__((ext_vector_type(4)));

__device__ __forceinline__ float fast_exp2(float x) { return exp2f(x); }
__device__ __forceinline__ float fast_rcp(float x)  { return __frcp_rn(x) ; }

#define MFMA(a, b, c) __builtin_amdgcn_mfma_f32_16x16x32_bf16((a), (b), (c), 0, 0, 0)

__device__ __forceinline__ unsigned short bfbits(float f) {
  bf16_t h = (bf16_t)f;
  return __builtin_bit_cast(unsigned short, h);
}

// ---------------------------------------------------------------------------
// Self-contained projection GEMM (convert fused in-block; ws holds ONLY C —
// the round-1-proven handoff topology; round 2's early-written bf16 planes
// were poisoned on graph replay).
// C[m][n] = sum_k A[m][k]*Wa[z*512+k][n], M=2048 K=512 N=512, x2 z.
// Block: 64m x 128n, 512 thr = 8 waves in 2m x 4n grid of 32x32 wave-tiles.
// BK=64. 3-term bf16 hi/lo split (~fp32 accuracy, absmax 1.95e-3 proven).
// ---------------------------------------------------------------------------
__global__ __launch_bounds__(512) void proj_gemm(
    const float* __restrict__ h_t, const float* __restrict__ srcp,
    const float* __restrict__ Wa, float* __restrict__ C)
{
  const int z = blockIdx.z;
  const float* __restrict__ A = z ? srcp : h_t;
  const int mbase = blockIdx.x * 64;
  const int nbase = blockIdx.y * 128;

  // pad rows to 72 elems: 16B-aligned rows, lane-stride 36 words = 4 banks
  __shared__ bf16_t Ah[64][72];
  __shared__ bf16_t Al[64][72];
  __shared__ bf16_t Bh[128][72];   // transposed: Bh[n][k]
  __shared__ bf16_t Bl[128][72];

  const int tid  = threadIdx.x;
  const int lane = tid & 63;
  const int wv   = tid >> 6;          // 0..7
  const int wm   = (wv & 1) * 32;
  const int wn   = (wv >> 1) * 32;    // 0,32,64,96
  const int l15  = lane & 15;
  const int qd   = lane >> 4;

  // A staging map: row = tid>>3 (0..63), k-chunk = (tid&7)*8
  const int arow = tid >> 3;
  const int akc  = (tid & 7) * 8;
  // B staging map: k-pair = tid>>4 (0..31), n base = tid&15 (stride-16 j-loop)
  const int kp = tid >> 4;
  const int nb = tid & 15;

  const float* Aptr = A + (size_t)(mbase + arow) * HID + akc;
  const float* Bptr = Wa + (size_t)(z * HID + 2 * kp) * ATT + nbase + nb;

  f32x4 acc00 = {0.f, 0.f, 0.f, 0.f};
  f32x4 acc01 = acc00, acc10 = acc00, acc11 = acc00;

  for (int kb = 0; kb < HID; kb += 64) {
    if (kb) __syncthreads();

    // ---- stage A (row-major [m][k]) hi/lo ----
    {
      float4 a0 = *(const float4*)(Aptr + kb);
      float4 a1 = *(const float4*)(Aptr + kb + 4);
      float av[8] = {a0.x, a0.y, a0.z, a0.w, a1.x, a1.y, a1.z, a1.w};
      bf16x8 hi, lo;
#pragma unroll
      for (int j = 0; j < 8; ++j) {
        bf16_t h = (bf16_t)av[j];
        hi[j] = h;
        lo[j] = (bf16_t)(av[j] - (float)h);
      }
      *(bf16x8*)&Ah[arow][akc] = hi;
      *(bf16x8*)&Al[arow][akc] = lo;
    }

    // ---- stage B transposed [n][k], packed k-pair b32 writes ----
    {
      const float* bp = Bptr + (size_t)kb * ATT;
#pragma unroll
      for (int j = 0; j < 8; ++j) {
        float w0 = bp[16 * j];
        float w1 = bp[ATT + 16 * j];
        bf16_t h0 = (bf16_t)w0, h1 = (bf16_t)w1;
        float lo0 = w0 - (float)h0, lo1 = w1 - (float)h1;
        unsigned int uh = (unsigned int)__builtin_bit_cast(unsigned short, h0) |
                          ((unsigned int)__builtin_bit_cast(unsigned short, h1) << 16);
        unsigned int ul = (unsigned int)bfbits(lo0) | ((unsigned int)bfbits(lo1) << 16);
        *(unsigned int*)&Bh[nb + 16 * j][2 * kp] = uh;
        *(unsigned int*)&Bl[nb + 16 * j][2 * kp] = ul;
      }
    }
    __syncthreads();

    // ---- compute: two K=32 halves, 12 MFMA each ----
#pragma unroll
    for (int h = 0; h < 2; ++h) {
      const int kh = h * 32 + qd * 8;
      bf16x8 ah0 = *(const bf16x8*)&Ah[wm + l15][kh];
      bf16x8 ah1 = *(const bf16x8*)&Ah[wm + 16 + l15][kh];
      bf16x8 al0 = *(const bf16x8*)&Al[wm + l15][kh];
      bf16x8 al1 = *(const bf16x8*)&Al[wm + 16 + l15][kh];
      bf16x8 bh0 = *(const bf16x8*)&Bh[wn + l15][kh];
      bf16x8 bh1 = *(const bf16x8*)&Bh[wn + 16 + l15][kh];
      bf16x8 bl0 = *(const bf16x8*)&Bl[wn + l15][kh];
      bf16x8 bl1 = *(const bf16x8*)&Bl[wn + 16 + l15][kh];

      acc00 = MFMA(ah0, bh0, acc00);
      acc01 = MFMA(ah0, bh1, acc01);
      acc10 = MFMA(ah1, bh0, acc10);
      acc11 = MFMA(ah1, bh1, acc11);
      acc00 = MFMA(al0, bh0, acc00);
      acc01 = MFMA(al0, bh1, acc01);
      acc10 = MFMA(al1, bh0, acc10);
      acc11 = MFMA(al1, bh1, acc11);
      acc00 = MFMA(ah0, bl0, acc00);
      acc01 = MFMA(ah0, bl1, acc01);
      acc10 = MFMA(ah1, bl0, acc10);
      acc11 = MFMA(ah1, bl1, acc11);
    }
  }

  // C/D layout: row = quad*4 + reg, col = lane&15  [measured m89/m91]
  float* Cz = C + (size_t)z * (MROWS * ATT);
#pragma unroll
  for (int r = 0; r < 4; ++r) {
    int row0 = mbase + wm + qd * 4 + r;
    int row1 = row0 + 16;
    int col0 = nbase + wn + l15;
    Cz[(size_t)row0 * ATT + col0]      = acc00[r];
    Cz[(size_t)row0 * ATT + col0 + 16] = acc01[r];
    Cz[(size_t)row1 * ATT + col0]      = acc10[r];
    Cz[(size_t)row1 * ATT + col0 + 16] = acc11[r];
  }
}

// ---------------------------------------------------------------------------
// Fused scores + softmax + context. One block per (4 targets, batch b).
// Wave w handles s = w*16..w*16+15; lane covers 8 a-elements.
// tanh·v sum via: sum(v·tanh) = sum(v) - 2·sum(v·rcp(1+exp2(x'))),
// with args pre-scaled by 2·log2(e).
// ---------------------------------------------------------------------------
__global__ __launch_bounds__(256) void attn_fused(
    const float* __restrict__ ws, const float* __restrict__ srcp,
    const float* __restrict__ Va, float* __restrict__ out)
{
  const float* __restrict__ h_part = ws;
  const float* __restrict__ s_part = ws + (size_t)TGT * BATCH * ATT;
  const float SC = 2.8853900817779268f;   // 2*log2(e)

  const int t0   = blockIdx.x * 4;
  const int b    = blockIdx.y;
  const int tid  = threadIdx.x;
  const int lane = tid & 63;
  const int wv   = tid >> 6;

  __shared__ float scoreLds[4][64];
  __shared__ float attnLds[4][64];

  const int abase = lane * 8;
  float va[8], H[4][8];
  *(float4*)&va[0] = *(const float4*)(Va + abase);
  *(float4*)&va[4] = *(const float4*)(Va + abase + 4);

  float vsum = 0.f;
#pragma unroll
  for (int j = 0; j < 8; ++j) vsum += va[j];
#pragma unroll
  for (int off = 32; off; off >>= 1) vsum += __shfl_xor(vsum, off);

#pragma unroll
  for (int t = 0; t < 4; ++t) {
    const float* hp = h_part + ((size_t)(t0 + t) * BATCH + b) * ATT + abase;
    float4 h0 = *(const float4*)hp;
    float4 h1 = *(const float4*)(hp + 4);
    H[t][0] = h0.x * SC; H[t][1] = h0.y * SC; H[t][2] = h0.z * SC; H[t][3] = h0.w * SC;
    H[t][4] = h1.x * SC; H[t][5] = h1.y * SC; H[t][6] = h1.z * SC; H[t][7] = h1.w * SC;
  }

  // ---- scores ----
#pragma unroll 2
  for (int i = 0; i < 16; ++i) {
    const int s = wv * 16 + i;
    const float* sp = s_part + ((size_t)s * BATCH + b) * ATT + abase;
    float4 s0 = *(const float4*)sp;
    float4 s1 = *(const float4*)(sp + 4);
    float sv[8] = {s0.x * SC, s0.y * SC, s0.z * SC, s0.w * SC,
                   s1.x * SC, s1.y * SC, s1.z * SC, s1.w * SC};
    float q0 = 0.f, q1 = 0.f, q2 = 0.f, q3 = 0.f;
#pragma unroll
    for (int j = 0; j < 8; ++j) {
      float xv = sv[j];
      float vj = va[j];
      q0 = fmaf(vj, fast_rcp(fast_exp2(xv + H[0][j]) + 1.0f), q0);
      q1 = fmaf(vj, fast_rcp(fast_exp2(xv + H[1][j]) + 1.0f), q1);
      q2 = fmaf(vj, fast_rcp(fast_exp2(xv + H[2][j]) + 1.0f), q2);
      q3 = fmaf(vj, fast_rcp(fast_exp2(xv + H[3][j]) + 1.0f), q3);
    }
#pragma unroll
    for (int off = 32; off; off >>= 1) {
      q0 += __shfl_xor(q0, off);
      q1 += __shfl_xor(q1, off);
      q2 += __shfl_xor(q2, off);
      q3 += __shfl_xor(q3, off);
    }
    if (lane == 0) {
      scoreLds[0][s] = vsum - 2.0f * q0;
      scoreLds[1][s] = vsum - 2.0f * q1;
      scoreLds[2][s] = vsum - 2.0f * q2;
      scoreLds[3][s] = vsum - 2.0f * q3;
    }
  }
  __syncthreads();

  // ---- softmax over s (axis 0): wave w handles t = w, lane = s ----
  {
    float sc = scoreLds[wv][lane];
    float m = sc;
#pragma unroll
    for (int off = 32; off; off >>= 1) m = fmaxf(m, __shfl_xor(m, off));
    float e = fast_exp2((sc - m) * 1.4426950408889634f);
    float ssum = e;
#pragma unroll
    for (int off = 32; off; off >>= 1) ssum += __shfl_xor(ssum, off);
    attnLds[wv][lane] = e * fast_rcp(ssum);
  }
  __syncthreads();

  // ---- context: out[t,b,h] = sum_s attn[s][t] * src[s,b,h] ----
  const int hp2 = tid * 2;
  float2 c0 = {0.f, 0.f}, c1 = c0, c2 = c0, c3 = c0;
  const float* sb = srcp + (size_t)b * HID + hp2;
#pragma unroll 4
  for (int s = 0; s < SRCN; ++s) {
    float2 sv = *(const float2*)(sb + (size_t)s * BATCH * HID);
    float a0 = attnLds[0][s], a1 = attnLds[1][s];
    float a2 = attnLds[2][s], a3 = attnLds[3][s];
    c0.x = fmaf(a0, sv.x, c0.x); c0.y = fmaf(a0, sv.y, c0.y);
    c1.x = fmaf(a1, sv.x, c1.x); c1.y = fmaf(a1, sv.y, c1.y);
    c2.x = fmaf(a2, sv.x, c2.x); c2.y = fmaf(a2, sv.y, c2.y);
    c3.x = fmaf(a3, sv.x, c3.x); c3.y = fmaf(a3, sv.y, c3.y);
  }
  *(float2*)(out + ((size_t)(t0 + 0) * BATCH + b) * HID + hp2) = c0;
  *(float2*)(out + ((size_t)(t0 + 1) * BATCH + b) * HID + hp2) = c1;
  *(float2*)(out + ((size_t)(t0 + 2) * BATCH + b) * HID + hp2) = c2;
  *(float2*)(out + ((size_t)(t0 + 3) * BATCH + b) * HID + hp2) = c3;
}

extern "C" void kernel_launch(void* const* d_in, const int* in_sizes, int n_in,
                              void* d_out, int out_size, void* d_ws, size_t ws_size,
                              hipStream_t stream) {
  const float* h_t = (const float*)d_in[0];   // (64,32,512)
  const float* src = (const float*)d_in[1];   // (64,32,512)
  const float* Wa  = (const float*)d_in[2];   // (1024,512)
  const float* Va  = (const float*)d_in[3];   // (512,)
  float* out = (float*)d_out;                 // (64,32,512)
  float* C   = (float*)d_ws;                  // 8 MB: h_part + s_part fp32 [z][2048][512]

  proj_gemm<<<dim3(32, 4, 2), 512, 0, stream>>>(h_t, src, Wa, C);
  attn_fused<<<dim3(16, 32), 256, 0, stream>>>(C, src, Va, out);
}

// Round 4
// 103.626 us; speedup vs baseline: 1.2862x; 1.2862x over previous
//
#include <hip/hip_runtime.h>
#include <hip/hip_bf16.h>

#define TGT   64
#define SRCN  64
#define BATCH 32
#define HID   512
#define ATT   512
#define MROWS (TGT * BATCH)          // 2048 rows per z

typedef __bf16 bf16_t;
typedef __bf16 bf16x8 __attribute__((ext_vector_type(8)));
typedef float  f32x4  __attribute__((ext_vector_type(4)));

// HW transcendentals: v_exp_f32 / v_rcp_f32 (quarter-rate, ~1 ulp).
// Round-3 lesson: exp2f (OCML precise) + __frcp_rn (correctly-rounded chain)
// cost ~25 instr/elem and made attn_fused 61 us. Builtin first, asm fallback
// (with s_nop for the trans->VALU hazard) so we can never fall back to libm.
__device__ __forceinline__ float fast_exp2(float x) {
#if __has_builtin(__builtin_amdgcn_exp2f)
  return __builtin_amdgcn_exp2f(x);
#else
  float r; asm("v_exp_f32 %0, %1\n\ts_nop 1" : "=v"(r) : "v"(x)); return r;
#endif
}
__device__ __forceinline__ float fast_rcp(float x) {
#if __has_builtin(__builtin_amdgcn_rcpf)
  return __builtin_amdgcn_rcpf(x);
#else
  float r; asm("v_rcp_f32 %0, %1\n\ts_nop 1" : "=v"(r) : "v"(x)); return r;
#endif
}

#define MFMA(a, b, c) __builtin_amdgcn_mfma_f32_16x16x32_bf16((a), (b), (c), 0, 0, 0)

__device__ __forceinline__ unsigned short bfbits(float f) {
  bf16_t h = (bf16_t)f;
  return __builtin_bit_cast(unsigned short, h);
}

// ---------------------------------------------------------------------------
// Projection GEMM — UNCHANGED from round 3 (est ~28 us; counters next round).
// ---------------------------------------------------------------------------
__global__ __launch_bounds__(512) void proj_gemm(
    const float* __restrict__ h_t, const float* __restrict__ srcp,
    const float* __restrict__ Wa, float* __restrict__ C)
{
  const int z = blockIdx.z;
  const float* __restrict__ A = z ? srcp : h_t;
  const int mbase = blockIdx.x * 64;
  const int nbase = blockIdx.y * 128;

  __shared__ bf16_t Ah[64][72];
  __shared__ bf16_t Al[64][72];
  __shared__ bf16_t Bh[128][72];   // transposed: Bh[n][k]
  __shared__ bf16_t Bl[128][72];

  const int tid  = threadIdx.x;
  const int lane = tid & 63;
  const int wv   = tid >> 6;          // 0..7
  const int wm   = (wv & 1) * 32;
  const int wn   = (wv >> 1) * 32;    // 0,32,64,96
  const int l15  = lane & 15;
  const int qd   = lane >> 4;

  const int arow = tid >> 3;
  const int akc  = (tid & 7) * 8;
  const int kp = tid >> 4;
  const int nb = tid & 15;

  const float* Aptr = A + (size_t)(mbase + arow) * HID + akc;
  const float* Bptr = Wa + (size_t)(z * HID + 2 * kp) * ATT + nbase + nb;

  f32x4 acc00 = {0.f, 0.f, 0.f, 0.f};
  f32x4 acc01 = acc00, acc10 = acc00, acc11 = acc00;

  for (int kb = 0; kb < HID; kb += 64) {
    if (kb) __syncthreads();

    {
      float4 a0 = *(const float4*)(Aptr + kb);
      float4 a1 = *(const float4*)(Aptr + kb + 4);
      float av[8] = {a0.x, a0.y, a0.z, a0.w, a1.x, a1.y, a1.z, a1.w};
      bf16x8 hi, lo;
#pragma unroll
      for (int j = 0; j < 8; ++j) {
        bf16_t h = (bf16_t)av[j];
        hi[j] = h;
        lo[j] = (bf16_t)(av[j] - (float)h);
      }
      *(bf16x8*)&Ah[arow][akc] = hi;
      *(bf16x8*)&Al[arow][akc] = lo;
    }

    {
      const float* bp = Bptr + (size_t)kb * ATT;
#pragma unroll
      for (int j = 0; j < 8; ++j) {
        float w0 = bp[16 * j];
        float w1 = bp[ATT + 16 * j];
        bf16_t h0 = (bf16_t)w0, h1 = (bf16_t)w1;
        float lo0 = w0 - (float)h0, lo1 = w1 - (float)h1;
        unsigned int uh = (unsigned int)__builtin_bit_cast(unsigned short, h0) |
                          ((unsigned int)__builtin_bit_cast(unsigned short, h1) << 16);
        unsigned int ul = (unsigned int)bfbits(lo0) | ((unsigned int)bfbits(lo1) << 16);
        *(unsigned int*)&Bh[nb + 16 * j][2 * kp] = uh;
        *(unsigned int*)&Bl[nb + 16 * j][2 * kp] = ul;
      }
    }
    __syncthreads();

#pragma unroll
    for (int h = 0; h < 2; ++h) {
      const int kh = h * 32 + qd * 8;
      bf16x8 ah0 = *(const bf16x8*)&Ah[wm + l15][kh];
      bf16x8 ah1 = *(const bf16x8*)&Ah[wm + 16 + l15][kh];
      bf16x8 al0 = *(const bf16x8*)&Al[wm + l15][kh];
      bf16x8 al1 = *(const bf16x8*)&Al[wm + 16 + l15][kh];
      bf16x8 bh0 = *(const bf16x8*)&Bh[wn + l15][kh];
      bf16x8 bh1 = *(const bf16x8*)&Bh[wn + 16 + l15][kh];
      bf16x8 bl0 = *(const bf16x8*)&Bl[wn + l15][kh];
      bf16x8 bl1 = *(const bf16x8*)&Bl[wn + 16 + l15][kh];

      acc00 = MFMA(ah0, bh0, acc00);
      acc01 = MFMA(ah0, bh1, acc01);
      acc10 = MFMA(ah1, bh0, acc10);
      acc11 = MFMA(ah1, bh1, acc11);
      acc00 = MFMA(al0, bh0, acc00);
      acc01 = MFMA(al0, bh1, acc01);
      acc10 = MFMA(al1, bh0, acc10);
      acc11 = MFMA(al1, bh1, acc11);
      acc00 = MFMA(ah0, bl0, acc00);
      acc01 = MFMA(ah0, bl1, acc01);
      acc10 = MFMA(ah1, bl0, acc10);
      acc11 = MFMA(ah1, bl1, acc11);
    }
  }

  float* Cz = C + (size_t)z * (MROWS * ATT);
#pragma unroll
  for (int r = 0; r < 4; ++r) {
    int row0 = mbase + wm + qd * 4 + r;
    int row1 = row0 + 16;
    int col0 = nbase + wn + l15;
    Cz[(size_t)row0 * ATT + col0]      = acc00[r];
    Cz[(size_t)row0 * ATT + col0 + 16] = acc01[r];
    Cz[(size_t)row1 * ATT + col0]      = acc10[r];
    Cz[(size_t)row1 * ATT + col0 + 16] = acc11[r];
  }
}

// ---------------------------------------------------------------------------
// Fused scores + softmax + context. Block = 512 thr (8 waves) per
// (4 targets, batch b); wave w handles s = w*8..w*8+7 (2x the occupancy of
// round 3's 256-thr version, to hide v_exp latency).
// sum(v*tanh(x)) = sum(v) - 2*sum(v*rcp(1+exp2(x'))), x' pre-scaled 2*log2(e).
// ---------------------------------------------------------------------------
__global__ __launch_bounds__(512) void attn_fused(
    const float* __restrict__ ws, const float* __restrict__ srcp,
    const float* __restrict__ Va, float* __restrict__ out)
{
  const float* __restrict__ h_part = ws;
  const float* __restrict__ s_part = ws + (size_t)TGT * BATCH * ATT;
  const float SC = 2.8853900817779268f;   // 2*log2(e)

  const int t0   = blockIdx.x * 4;
  const int b    = blockIdx.y;
  const int tid  = threadIdx.x;
  const int lane = tid & 63;
  const int wv   = tid >> 6;              // 0..7

  __shared__ float scoreLds[4][64];
  __shared__ float attnLds[4][64];

  const int abase = lane * 8;
  float va[8], H[4][8];
  *(float4*)&va[0] = *(const float4*)(Va + abase);
  *(float4*)&va[4] = *(const float4*)(Va + abase + 4);

  float vsum = 0.f;
#pragma unroll
  for (int j = 0; j < 8; ++j) vsum += va[j];
#pragma unroll
  for (int off = 32; off; off >>= 1) vsum += __shfl_xor(vsum, off);

#pragma unroll
  for (int t = 0; t < 4; ++t) {
    const float* hp = h_part + ((size_t)(t0 + t) * BATCH + b) * ATT + abase;
    float4 h0 = *(const float4*)hp;
    float4 h1 = *(const float4*)(hp + 4);
    H[t][0] = h0.x * SC; H[t][1] = h0.y * SC; H[t][2] = h0.z * SC; H[t][3] = h0.w * SC;
    H[t][4] = h1.x * SC; H[t][5] = h1.y * SC; H[t][6] = h1.z * SC; H[t][7] = h1.w * SC;
  }

  // ---- scores: 8 s-rows per wave ----
#pragma unroll 2
  for (int i = 0; i < 8; ++i) {
    const int s = wv * 8 + i;
    const float* sp = s_part + ((size_t)s * BATCH + b) * ATT + abase;
    float4 s0 = *(const float4*)sp;
    float4 s1 = *(const float4*)(sp + 4);
    float sv[8] = {s0.x * SC, s0.y * SC, s0.z * SC, s0.w * SC,
                   s1.x * SC, s1.y * SC, s1.z * SC, s1.w * SC};
    float q0 = 0.f, q1 = 0.f, q2 = 0.f, q3 = 0.f;
#pragma unroll
    for (int j = 0; j < 8; ++j) {
      float xv = sv[j];
      float vj = va[j];
      q0 = fmaf(vj, fast_rcp(fast_exp2(xv + H[0][j]) + 1.0f), q0);
      q1 = fmaf(vj, fast_rcp(fast_exp2(xv + H[1][j]) + 1.0f), q1);
      q2 = fmaf(vj, fast_rcp(fast_exp2(xv + H[2][j]) + 1.0f), q2);
      q3 = fmaf(vj, fast_rcp(fast_exp2(xv + H[3][j]) + 1.0f), q3);
    }
#pragma unroll
    for (int off = 32; off; off >>= 1) {
      q0 += __shfl_xor(q0, off);
      q1 += __shfl_xor(q1, off);
      q2 += __shfl_xor(q2, off);
      q3 += __shfl_xor(q3, off);
    }
    if (lane == 0) {
      scoreLds[0][s] = vsum - 2.0f * q0;
      scoreLds[1][s] = vsum - 2.0f * q1;
      scoreLds[2][s] = vsum - 2.0f * q2;
      scoreLds[3][s] = vsum - 2.0f * q3;
    }
  }
  __syncthreads();

  // ---- softmax over s: waves 0..3 handle t = wv, lane = s ----
  if (wv < 4) {
    float sc = scoreLds[wv][lane];
    float m = sc;
#pragma unroll
    for (int off = 32; off; off >>= 1) m = fmaxf(m, __shfl_xor(m, off));
    float e = fast_exp2((sc - m) * 1.4426950408889634f);
    float ssum = e;
#pragma unroll
    for (int off = 32; off; off >>= 1) ssum += __shfl_xor(ssum, off);
    attnLds[wv][lane] = e * fast_rcp(ssum);
  }
  __syncthreads();

  // ---- context: thread h = tid covers one of 512 hidden dims ----
  {
    float c0 = 0.f, c1 = 0.f, c2 = 0.f, c3 = 0.f;
    const float* sb = srcp + (size_t)b * HID + tid;
#pragma unroll 8
    for (int s = 0; s < SRCN; ++s) {
      float sv = sb[(size_t)s * BATCH * HID];
      c0 = fmaf(attnLds[0][s], sv, c0);
      c1 = fmaf(attnLds[1][s], sv, c1);
      c2 = fmaf(attnLds[2][s], sv, c2);
      c3 = fmaf(attnLds[3][s], sv, c3);
    }
    out[((size_t)(t0 + 0) * BATCH + b) * HID + tid] = c0;
    out[((size_t)(t0 + 1) * BATCH + b) * HID + tid] = c1;
    out[((size_t)(t0 + 2) * BATCH + b) * HID + tid] = c2;
    out[((size_t)(t0 + 3) * BATCH + b) * HID + tid] = c3;
  }
}

extern "C" void kernel_launch(void* const* d_in, const int* in_sizes, int n_in,
                              void* d_out, int out_size, void* d_ws, size_t ws_size,
                              hipStream_t stream) {
  const float* h_t = (const float*)d_in[0];   // (64,32,512)
  const float* src = (const float*)d_in[1];   // (64,32,512)
  const float* Wa  = (const float*)d_in[2];   // (1024,512)
  const float* Va  = (const float*)d_in[3];   // (512,)
  float* out = (float*)d_out;                 // (64,32,512)
  float* C   = (float*)d_ws;                  // 8 MB: h_part + s_part fp32 [z][2048][512]

  proj_gemm<<<dim3(32, 4, 2), 512, 0, stream>>>(h_t, src, Wa, C);
  attn_fused<<<dim3(16, 32), 512, 0, stream>>>(C, src, Va, out);
}

// Round 5
// 100.313 us; speedup vs baseline: 1.3287x; 1.0330x over previous
//
#include <hip/hip_runtime.h>
#include <hip/hip_bf16.h>

#define TGT   64
#define SRCN  64
#define BATCH 32
#define HID   512
#define ATT   512
#define MROWS (TGT * BATCH)          // 2048 rows per z

typedef __bf16 bf16_t;
typedef __bf16 bf16x8 __attribute__((ext_vector_type(8)));
typedef float  f32x4  __attribute__((ext_vector_type(4)));

// HW transcendentals (round-3 lesson: libm exp2f/__frcp_rn cost 29 us).
__device__ __forceinline__ float fast_exp2(float x) {
#if __has_builtin(__builtin_amdgcn_exp2f)
  return __builtin_amdgcn_exp2f(x);
#else
  float r; asm("v_exp_f32 %0, %1\n\ts_nop 1" : "=v"(r) : "v"(x)); return r;
#endif
}
__device__ __forceinline__ float fast_rcp(float x) {
#if __has_builtin(__builtin_amdgcn_rcpf)
  return __builtin_amdgcn_rcpf(x);
#else
  float r; asm("v_rcp_f32 %0, %1\n\ts_nop 1" : "=v"(r) : "v"(x)); return r;
#endif
}

#define MFMA(a, b, c) __builtin_amdgcn_mfma_f32_16x16x32_bf16((a), (b), (c), 0, 0, 0)

// ---------------------------------------------------------------------------
// proj_gemm v2. C[m][n] = sum_k A[m][k]*Wa[z*512+k][n]; M=2048 K=512 N=512, x2 z.
// Block: 64m x 64n, 256 thr = 4 waves (2x2 of 32x32 wave-tiles), BK=64.
// Grid 512 blocks -> 2 blocks/CU (TLP hides barrier drain; R4 had 1/CU).
// B staged transposed [n][k] via column-coalesced loads (lane=n, 256B/instr)
// and 4x ds_write_b128 per thread (was 16x ds_write_b32).
// 3-term bf16 hi/lo split (absmax 1.95e-3 proven R1/R3/R4).
// ws holds ONLY C (round-2 lesson: early-written ws planes get clobbered
// by the harness's concurrent 41us poison fill on graph replay).
// ---------------------------------------------------------------------------
__global__ __launch_bounds__(256) void proj_gemm(
    const float* __restrict__ h_t, const float* __restrict__ srcp,
    const float* __restrict__ Wa, float* __restrict__ C)
{
  const int z = blockIdx.z;
  const float* __restrict__ A = z ? srcp : h_t;
  const int mbase = blockIdx.x * 64;
  const int nbase = blockIdx.y * 64;

  // rows padded to 72 elems: 16B-aligned, lane-stride 36 words -> 2-way banks (free)
  __shared__ bf16_t Ah[64][72];
  __shared__ bf16_t Al[64][72];
  __shared__ bf16_t Bh[64][72];   // transposed: Bh[n][k]
  __shared__ bf16_t Bl[64][72];

  const int tid  = threadIdx.x;
  const int lane = tid & 63;
  const int wv   = tid >> 6;          // 0..3
  const int wm   = (wv & 1) * 32;
  const int wn   = (wv >> 1) * 32;
  const int l15  = lane & 15;
  const int qd   = lane >> 4;

  // A staging: row = tid>>2 (0..63), k-chunk = (tid&3)*16
  const int arow = tid >> 2;
  const int akc  = (tid & 3) * 16;
  // B staging: n = tid&63, k-group = (tid>>6)*16 (one group per wave)
  const int bn = tid & 63;
  const int bkg = (tid >> 6) * 16;

  const float* Aptr = A + (size_t)(mbase + arow) * HID + akc;
  const float* Bptr = Wa + (size_t)(z * HID + bkg) * ATT + nbase + bn;

  f32x4 acc00 = {0.f, 0.f, 0.f, 0.f};
  f32x4 acc01 = acc00, acc10 = acc00, acc11 = acc00;

  for (int kb = 0; kb < HID; kb += 64) {
    if (kb) __syncthreads();

    // ---- stage A (row-major [m][k]) hi/lo: 4 float4 loads, 4 b128 writes ----
    {
      float4 a0 = *(const float4*)(Aptr + kb);
      float4 a1 = *(const float4*)(Aptr + kb + 4);
      float4 a2 = *(const float4*)(Aptr + kb + 8);
      float4 a3 = *(const float4*)(Aptr + kb + 12);
      float av[16] = {a0.x, a0.y, a0.z, a0.w, a1.x, a1.y, a1.z, a1.w,
                      a2.x, a2.y, a2.z, a2.w, a3.x, a3.y, a3.z, a3.w};
      bf16x8 hi0, hi1, lo0, lo1;
#pragma unroll
      for (int j = 0; j < 8; ++j) {
        bf16_t h = (bf16_t)av[j];
        hi0[j] = h;
        lo0[j] = (bf16_t)(av[j] - (float)h);
        bf16_t h2 = (bf16_t)av[j + 8];
        hi1[j] = h2;
        lo1[j] = (bf16_t)(av[j + 8] - (float)h2);
      }
      *(bf16x8*)&Ah[arow][akc]     = hi0;
      *(bf16x8*)&Ah[arow][akc + 8] = hi1;
      *(bf16x8*)&Al[arow][akc]     = lo0;
      *(bf16x8*)&Al[arow][akc + 8] = lo1;
    }

    // ---- stage B transposed [n][k]: 16 coalesced k-row loads, 4 b128 writes ----
    {
      const float* bp = Bptr + (size_t)kb * ATT;
      float bv[16];
#pragma unroll
      for (int j = 0; j < 16; ++j) bv[j] = bp[(size_t)j * ATT];
      bf16x8 hi0, hi1, lo0, lo1;
#pragma unroll
      for (int j = 0; j < 8; ++j) {
        bf16_t h = (bf16_t)bv[j];
        hi0[j] = h;
        lo0[j] = (bf16_t)(bv[j] - (float)h);
        bf16_t h2 = (bf16_t)bv[j + 8];
        hi1[j] = h2;
        lo1[j] = (bf16_t)(bv[j + 8] - (float)h2);
      }
      *(bf16x8*)&Bh[bn][bkg]     = hi0;
      *(bf16x8*)&Bh[bn][bkg + 8] = hi1;
      *(bf16x8*)&Bl[bn][bkg]     = lo0;
      *(bf16x8*)&Bl[bn][bkg + 8] = lo1;
    }
    __syncthreads();

    // ---- compute: two K=32 halves, 12 MFMA each ----
#pragma unroll
    for (int h = 0; h < 2; ++h) {
      const int kh = h * 32 + qd * 8;
      bf16x8 ah0 = *(const bf16x8*)&Ah[wm + l15][kh];
      bf16x8 ah1 = *(const bf16x8*)&Ah[wm + 16 + l15][kh];
      bf16x8 al0 = *(const bf16x8*)&Al[wm + l15][kh];
      bf16x8 al1 = *(const bf16x8*)&Al[wm + 16 + l15][kh];
      bf16x8 bh0 = *(const bf16x8*)&Bh[wn + l15][kh];
      bf16x8 bh1 = *(const bf16x8*)&Bh[wn + 16 + l15][kh];
      bf16x8 bl0 = *(const bf16x8*)&Bl[wn + l15][kh];
      bf16x8 bl1 = *(const bf16x8*)&Bl[wn + 16 + l15][kh];

      acc00 = MFMA(ah0, bh0, acc00);
      acc01 = MFMA(ah0, bh1, acc01);
      acc10 = MFMA(ah1, bh0, acc10);
      acc11 = MFMA(ah1, bh1, acc11);
      acc00 = MFMA(al0, bh0, acc00);
      acc01 = MFMA(al0, bh1, acc01);
      acc10 = MFMA(al1, bh0, acc10);
      acc11 = MFMA(al1, bh1, acc11);
      acc00 = MFMA(ah0, bl0, acc00);
      acc01 = MFMA(ah0, bl1, acc01);
      acc10 = MFMA(ah1, bl0, acc10);
      acc11 = MFMA(ah1, bl1, acc11);
    }
  }

  // C/D layout: row = quad*4 + reg, col = lane&15  [measured m89/m91]
  float* Cz = C + (size_t)z * (MROWS * ATT);
#pragma unroll
  for (int r = 0; r < 4; ++r) {
    int row0 = mbase + wm + qd * 4 + r;
    int row1 = row0 + 16;
    int col0 = nbase + wn + l15;
    Cz[(size_t)row0 * ATT + col0]      = acc00[r];
    Cz[(size_t)row0 * ATT + col0 + 16] = acc01[r];
    Cz[(size_t)row1 * ATT + col0]      = acc10[r];
    Cz[(size_t)row1 * ATT + col0 + 16] = acc11[r];
  }
}

// ---------------------------------------------------------------------------
// attn_fused — UNCHANGED from round 4 (isolates the proj delta).
// ---------------------------------------------------------------------------
__global__ __launch_bounds__(512) void attn_fused(
    const float* __restrict__ ws, const float* __restrict__ srcp,
    const float* __restrict__ Va, float* __restrict__ out)
{
  const float* __restrict__ h_part = ws;
  const float* __restrict__ s_part = ws + (size_t)TGT * BATCH * ATT;
  const float SC = 2.8853900817779268f;   // 2*log2(e)

  const int t0   = blockIdx.x * 4;
  const int b    = blockIdx.y;
  const int tid  = threadIdx.x;
  const int lane = tid & 63;
  const int wv   = tid >> 6;              // 0..7

  __shared__ float scoreLds[4][64];
  __shared__ float attnLds[4][64];

  const int abase = lane * 8;
  float va[8], H[4][8];
  *(float4*)&va[0] = *(const float4*)(Va + abase);
  *(float4*)&va[4] = *(const float4*)(Va + abase + 4);

  float vsum = 0.f;
#pragma unroll
  for (int j = 0; j < 8; ++j) vsum += va[j];
#pragma unroll
  for (int off = 32; off; off >>= 1) vsum += __shfl_xor(vsum, off);

#pragma unroll
  for (int t = 0; t < 4; ++t) {
    const float* hp = h_part + ((size_t)(t0 + t) * BATCH + b) * ATT + abase;
    float4 h0 = *(const float4*)hp;
    float4 h1 = *(const float4*)(hp + 4);
    H[t][0] = h0.x * SC; H[t][1] = h0.y * SC; H[t][2] = h0.z * SC; H[t][3] = h0.w * SC;
    H[t][4] = h1.x * SC; H[t][5] = h1.y * SC; H[t][6] = h1.z * SC; H[t][7] = h1.w * SC;
  }

  // ---- scores: 8 s-rows per wave ----
#pragma unroll 2
  for (int i = 0; i < 8; ++i) {
    const int s = wv * 8 + i;
    const float* sp = s_part + ((size_t)s * BATCH + b) * ATT + abase;
    float4 s0 = *(const float4*)sp;
    float4 s1 = *(const float4*)(sp + 4);
    float sv[8] = {s0.x * SC, s0.y * SC, s0.z * SC, s0.w * SC,
                   s1.x * SC, s1.y * SC, s1.z * SC, s1.w * SC};
    float q0 = 0.f, q1 = 0.f, q2 = 0.f, q3 = 0.f;
#pragma unroll
    for (int j = 0; j < 8; ++j) {
      float xv = sv[j];
      float vj = va[j];
      q0 = fmaf(vj, fast_rcp(fast_exp2(xv + H[0][j]) + 1.0f), q0);
      q1 = fmaf(vj, fast_rcp(fast_exp2(xv + H[1][j]) + 1.0f), q1);
      q2 = fmaf(vj, fast_rcp(fast_exp2(xv + H[2][j]) + 1.0f), q2);
      q3 = fmaf(vj, fast_rcp(fast_exp2(xv + H[3][j]) + 1.0f), q3);
    }
#pragma unroll
    for (int off = 32; off; off >>= 1) {
      q0 += __shfl_xor(q0, off);
      q1 += __shfl_xor(q1, off);
      q2 += __shfl_xor(q2, off);
      q3 += __shfl_xor(q3, off);
    }
    if (lane == 0) {
      scoreLds[0][s] = vsum - 2.0f * q0;
      scoreLds[1][s] = vsum - 2.0f * q1;
      scoreLds[2][s] = vsum - 2.0f * q2;
      scoreLds[3][s] = vsum - 2.0f * q3;
    }
  }
  __syncthreads();

  // ---- softmax over s: waves 0..3 handle t = wv, lane = s ----
  if (wv < 4) {
    float sc = scoreLds[wv][lane];
    float m = sc;
#pragma unroll
    for (int off = 32; off; off >>= 1) m = fmaxf(m, __shfl_xor(m, off));
    float e = fast_exp2((sc - m) * 1.4426950408889634f);
    float ssum = e;
#pragma unroll
    for (int off = 32; off; off >>= 1) ssum += __shfl_xor(ssum, off);
    attnLds[wv][lane] = e * fast_rcp(ssum);
  }
  __syncthreads();

  // ---- context: thread h = tid covers one of 512 hidden dims ----
  {
    float c0 = 0.f, c1 = 0.f, c2 = 0.f, c3 = 0.f;
    const float* sb = srcp + (size_t)b * HID + tid;
#pragma unroll 8
    for (int s = 0; s < SRCN; ++s) {
      float sv = sb[(size_t)s * BATCH * HID];
      c0 = fmaf(attnLds[0][s], sv, c0);
      c1 = fmaf(attnLds[1][s], sv, c1);
      c2 = fmaf(attnLds[2][s], sv, c2);
      c3 = fmaf(attnLds[3][s], sv, c3);
    }
    out[((size_t)(t0 + 0) * BATCH + b) * HID + tid] = c0;
    out[((size_t)(t0 + 1) * BATCH + b) * HID + tid] = c1;
    out[((size_t)(t0 + 2) * BATCH + b) * HID + tid] = c2;
    out[((size_t)(t0 + 3) * BATCH + b) * HID + tid] = c3;
  }
}

extern "C" void kernel_launch(void* const* d_in, const int* in_sizes, int n_in,
                              void* d_out, int out_size, void* d_ws, size_t ws_size,
                              hipStream_t stream) {
  const float* h_t = (const float*)d_in[0];   // (64,32,512)
  const float* src = (const float*)d_in[1];   // (64,32,512)
  const float* Wa  = (const float*)d_in[2];   // (1024,512)
  const float* Va  = (const float*)d_in[3];   // (512,)
  float* out = (float*)d_out;                 // (64,32,512)
  float* C   = (float*)d_ws;                  // 8 MB: h_part + s_part fp32 [z][2048][512]

  proj_gemm<<<dim3(32, 8, 2), 256, 0, stream>>>(h_t, src, Wa, C);
  attn_fused<<<dim3(16, 32), 512, 0, stream>>>(C, src, Va, out);
}

// Round 6
// 98.884 us; speedup vs baseline: 1.3479x; 1.0144x over previous
//
#include <hip/hip_runtime.h>
#include <hip/hip_bf16.h>

#define TGT   64
#define SRCN  64
#define BATCH 32
#define HID   512
#define ATT   512
#define MROWS (TGT * BATCH)          // 2048 rows per z

typedef __bf16 bf16_t;
typedef __bf16 bf16x8 __attribute__((ext_vector_type(8)));
typedef float  f32x4  __attribute__((ext_vector_type(4)));

// HW transcendentals (round-3 lesson: libm exp2f/__frcp_rn cost 29 us).
__device__ __forceinline__ float fast_exp2(float x) {
#if __has_builtin(__builtin_amdgcn_exp2f)
  return __builtin_amdgcn_exp2f(x);
#else
  float r; asm("v_exp_f32 %0, %1\n\ts_nop 1" : "=v"(r) : "v"(x)); return r;
#endif
}
__device__ __forceinline__ float fast_rcp(float x) {
#if __has_builtin(__builtin_amdgcn_rcpf)
  return __builtin_amdgcn_rcpf(x);
#else
  float r; asm("v_rcp_f32 %0, %1\n\ts_nop 1" : "=v"(r) : "v"(x)); return r;
#endif
}

#define MFMA(a, b, c) __builtin_amdgcn_mfma_f32_16x16x32_bf16((a), (b), (c), 0, 0, 0)

// ---------------------------------------------------------------------------
// proj_gemm v2 — UNCHANGED from round 5 (est ~19-22 us; isolates attn delta).
// ---------------------------------------------------------------------------
__global__ __launch_bounds__(256) void proj_gemm(
    const float* __restrict__ h_t, const float* __restrict__ srcp,
    const float* __restrict__ Wa, float* __restrict__ C)
{
  const int z = blockIdx.z;
  const float* __restrict__ A = z ? srcp : h_t;
  const int mbase = blockIdx.x * 64;
  const int nbase = blockIdx.y * 64;

  __shared__ bf16_t Ah[64][72];
  __shared__ bf16_t Al[64][72];
  __shared__ bf16_t Bh[64][72];   // transposed: Bh[n][k]
  __shared__ bf16_t Bl[64][72];

  const int tid  = threadIdx.x;
  const int lane = tid & 63;
  const int wv   = tid >> 6;          // 0..3
  const int wm   = (wv & 1) * 32;
  const int wn   = (wv >> 1) * 32;
  const int l15  = lane & 15;
  const int qd   = lane >> 4;

  const int arow = tid >> 2;
  const int akc  = (tid & 3) * 16;
  const int bn = tid & 63;
  const int bkg = (tid >> 6) * 16;

  const float* Aptr = A + (size_t)(mbase + arow) * HID + akc;
  const float* Bptr = Wa + (size_t)(z * HID + bkg) * ATT + nbase + bn;

  f32x4 acc00 = {0.f, 0.f, 0.f, 0.f};
  f32x4 acc01 = acc00, acc10 = acc00, acc11 = acc00;

  for (int kb = 0; kb < HID; kb += 64) {
    if (kb) __syncthreads();

    {
      float4 a0 = *(const float4*)(Aptr + kb);
      float4 a1 = *(const float4*)(Aptr + kb + 4);
      float4 a2 = *(const float4*)(Aptr + kb + 8);
      float4 a3 = *(const float4*)(Aptr + kb + 12);
      float av[16] = {a0.x, a0.y, a0.z, a0.w, a1.x, a1.y, a1.z, a1.w,
                      a2.x, a2.y, a2.z, a2.w, a3.x, a3.y, a3.z, a3.w};
      bf16x8 hi0, hi1, lo0, lo1;
#pragma unroll
      for (int j = 0; j < 8; ++j) {
        bf16_t h = (bf16_t)av[j];
        hi0[j] = h;
        lo0[j] = (bf16_t)(av[j] - (float)h);
        bf16_t h2 = (bf16_t)av[j + 8];
        hi1[j] = h2;
        lo1[j] = (bf16_t)(av[j + 8] - (float)h2);
      }
      *(bf16x8*)&Ah[arow][akc]     = hi0;
      *(bf16x8*)&Ah[arow][akc + 8] = hi1;
      *(bf16x8*)&Al[arow][akc]     = lo0;
      *(bf16x8*)&Al[arow][akc + 8] = lo1;
    }

    {
      const float* bp = Bptr + (size_t)kb * ATT;
      float bv[16];
#pragma unroll
      for (int j = 0; j < 16; ++j) bv[j] = bp[(size_t)j * ATT];
      bf16x8 hi0, hi1, lo0, lo1;
#pragma unroll
      for (int j = 0; j < 8; ++j) {
        bf16_t h = (bf16_t)bv[j];
        hi0[j] = h;
        lo0[j] = (bf16_t)(bv[j] - (float)h);
        bf16_t h2 = (bf16_t)bv[j + 8];
        hi1[j] = h2;
        lo1[j] = (bf16_t)(bv[j + 8] - (float)h2);
      }
      *(bf16x8*)&Bh[bn][bkg]     = hi0;
      *(bf16x8*)&Bh[bn][bkg + 8] = hi1;
      *(bf16x8*)&Bl[bn][bkg]     = lo0;
      *(bf16x8*)&Bl[bn][bkg + 8] = lo1;
    }
    __syncthreads();

#pragma unroll
    for (int h = 0; h < 2; ++h) {
      const int kh = h * 32 + qd * 8;
      bf16x8 ah0 = *(const bf16x8*)&Ah[wm + l15][kh];
      bf16x8 ah1 = *(const bf16x8*)&Ah[wm + 16 + l15][kh];
      bf16x8 al0 = *(const bf16x8*)&Al[wm + l15][kh];
      bf16x8 al1 = *(const bf16x8*)&Al[wm + 16 + l15][kh];
      bf16x8 bh0 = *(const bf16x8*)&Bh[wn + l15][kh];
      bf16x8 bh1 = *(const bf16x8*)&Bh[wn + 16 + l15][kh];
      bf16x8 bl0 = *(const bf16x8*)&Bl[wn + l15][kh];
      bf16x8 bl1 = *(const bf16x8*)&Bl[wn + 16 + l15][kh];

      acc00 = MFMA(ah0, bh0, acc00);
      acc01 = MFMA(ah0, bh1, acc01);
      acc10 = MFMA(ah1, bh0, acc10);
      acc11 = MFMA(ah1, bh1, acc11);
      acc00 = MFMA(al0, bh0, acc00);
      acc01 = MFMA(al0, bh1, acc01);
      acc10 = MFMA(al1, bh0, acc10);
      acc11 = MFMA(al1, bh1, acc11);
      acc00 = MFMA(ah0, bl0, acc00);
      acc01 = MFMA(ah0, bl1, acc01);
      acc10 = MFMA(ah1, bl0, acc10);
      acc11 = MFMA(ah1, bl1, acc11);
    }
  }

  float* Cz = C + (size_t)z * (MROWS * ATT);
#pragma unroll
  for (int r = 0; r < 4; ++r) {
    int row0 = mbase + wm + qd * 4 + r;
    int row1 = row0 + 16;
    int col0 = nbase + wn + l15;
    Cz[(size_t)row0 * ATT + col0]      = acc00[r];
    Cz[(size_t)row0 * ATT + col0 + 16] = acc01[r];
    Cz[(size_t)row1 * ATT + col0]      = acc10[r];
    Cz[(size_t)row1 * ATT + col0 + 16] = acc11[r];
  }
}

// ---------------------------------------------------------------------------
// attn_fused v3: 2 targets per block (was 4) -> 1024 blocks x 8 waves = 8192
// waves (6-8 waves/SIMD vs R4's 4) — extends the PROVEN R3->R4 TLP lever
// (waves/SIMD 2->4 halved attn 61->31 us). ~60 VGPR so 3-4 blocks/CU fit.
// Plus software-pipelined s-row prefetch to hide first-touch L2 latency.
// ---------------------------------------------------------------------------
__global__ __launch_bounds__(512) void attn_fused(
    const float* __restrict__ ws, const float* __restrict__ srcp,
    const float* __restrict__ Va, float* __restrict__ out)
{
  const float* __restrict__ h_part = ws;
  const float* __restrict__ s_part = ws + (size_t)TGT * BATCH * ATT;
  const float SC = 2.8853900817779268f;   // 2*log2(e)

  const int t0   = blockIdx.x * 2;
  const int b    = blockIdx.y;
  const int tid  = threadIdx.x;
  const int lane = tid & 63;
  const int wv   = tid >> 6;              // 0..7

  __shared__ float scoreLds[2][64];
  __shared__ float attnLds[2][64];

  const int abase = lane * 8;
  float va[8], H[2][8];
  *(float4*)&va[0] = *(const float4*)(Va + abase);
  *(float4*)&va[4] = *(const float4*)(Va + abase + 4);

  float vsum = 0.f;
#pragma unroll
  for (int j = 0; j < 8; ++j) vsum += va[j];
#pragma unroll
  for (int off = 32; off; off >>= 1) vsum += __shfl_xor(vsum, off);

#pragma unroll
  for (int t = 0; t < 2; ++t) {
    const float* hp = h_part + ((size_t)(t0 + t) * BATCH + b) * ATT + abase;
    float4 h0 = *(const float4*)hp;
    float4 h1 = *(const float4*)(hp + 4);
    H[t][0] = h0.x * SC; H[t][1] = h0.y * SC; H[t][2] = h0.z * SC; H[t][3] = h0.w * SC;
    H[t][4] = h1.x * SC; H[t][5] = h1.y * SC; H[t][6] = h1.z * SC; H[t][7] = h1.w * SC;
  }

  // ---- scores: 8 s-rows per wave, next-row prefetch pipeline ----
  const int s0 = wv * 8;
  const float* sp = s_part + ((size_t)s0 * BATCH + b) * ATT + abase;
  float4 p0 = *(const float4*)sp;
  float4 p1 = *(const float4*)(sp + 4);
#pragma unroll
  for (int i = 0; i < 8; ++i) {
    float4 n0, n1;
    if (i < 7) {
      const float* spn = s_part + ((size_t)(s0 + i + 1) * BATCH + b) * ATT + abase;
      n0 = *(const float4*)spn;
      n1 = *(const float4*)(spn + 4);
    }
    float sv[8] = {p0.x * SC, p0.y * SC, p0.z * SC, p0.w * SC,
                   p1.x * SC, p1.y * SC, p1.z * SC, p1.w * SC};
    float q0 = 0.f, q1 = 0.f;
#pragma unroll
    for (int j = 0; j < 8; ++j) {
      float xv = sv[j];
      float vj = va[j];
      q0 = fmaf(vj, fast_rcp(fast_exp2(xv + H[0][j]) + 1.0f), q0);
      q1 = fmaf(vj, fast_rcp(fast_exp2(xv + H[1][j]) + 1.0f), q1);
    }
#pragma unroll
    for (int off = 32; off; off >>= 1) {
      q0 += __shfl_xor(q0, off);
      q1 += __shfl_xor(q1, off);
    }
    if (lane == 0) {
      scoreLds[0][s0 + i] = vsum - 2.0f * q0;
      scoreLds[1][s0 + i] = vsum - 2.0f * q1;
    }
    p0 = n0;
    p1 = n1;
  }
  __syncthreads();

  // ---- softmax over s: waves 0..1 handle t = wv, lane = s ----
  if (wv < 2) {
    float sc = scoreLds[wv][lane];
    float m = sc;
#pragma unroll
    for (int off = 32; off; off >>= 1) m = fmaxf(m, __shfl_xor(m, off));
    float e = fast_exp2((sc - m) * 1.4426950408889634f);
    float ssum = e;
#pragma unroll
    for (int off = 32; off; off >>= 1) ssum += __shfl_xor(ssum, off);
    attnLds[wv][lane] = e * fast_rcp(ssum);
  }
  __syncthreads();

  // ---- context: thread h = tid covers one of 512 hidden dims ----
  {
    float c0 = 0.f, c1 = 0.f;
    const float* sb = srcp + (size_t)b * HID + tid;
#pragma unroll 8
    for (int s = 0; s < SRCN; ++s) {
      float sv = sb[(size_t)s * BATCH * HID];
      c0 = fmaf(attnLds[0][s], sv, c0);
      c1 = fmaf(attnLds[1][s], sv, c1);
    }
    out[((size_t)(t0 + 0) * BATCH + b) * HID + tid] = c0;
    out[((size_t)(t0 + 1) * BATCH + b) * HID + tid] = c1;
  }
}

extern "C" void kernel_launch(void* const* d_in, const int* in_sizes, int n_in,
                              void* d_out, int out_size, void* d_ws, size_t ws_size,
                              hipStream_t stream) {
  const float* h_t = (const float*)d_in[0];   // (64,32,512)
  const float* src = (const float*)d_in[1];   // (64,32,512)
  const float* Wa  = (const float*)d_in[2];   // (1024,512)
  const float* Va  = (const float*)d_in[3];   // (512,)
  float* out = (float*)d_out;                 // (64,32,512)
  float* C   = (float*)d_ws;                  // 8 MB: h_part + s_part fp32 [z][2048][512]

  proj_gemm<<<dim3(32, 8, 2), 256, 0, stream>>>(h_t, src, Wa, C);
  attn_fused<<<dim3(32, 32), 512, 0, stream>>>(C, src, Va, out);
}

// Round 7
// 97.822 us; speedup vs baseline: 1.3625x; 1.0109x over previous
//
#include <hip/hip_runtime.h>
#include <hip/hip_bf16.h>

#define TGT   64
#define SRCN  64
#define BATCH 32
#define HID   512
#define ATT   512
#define MROWS (TGT * BATCH)          // 2048 rows per z

typedef __bf16 bf16_t;
typedef __bf16 bf16x8 __attribute__((ext_vector_type(8)));
typedef float  f32x4  __attribute__((ext_vector_type(4)));

// HW transcendentals (round-3 lesson: libm exp2f/__frcp_rn cost 29 us).
__device__ __forceinline__ float fast_exp2(float x) {
#if __has_builtin(__builtin_amdgcn_exp2f)
  return __builtin_amdgcn_exp2f(x);
#else
  float r; asm("v_exp_f32 %0, %1\n\ts_nop 1" : "=v"(r) : "v"(x)); return r;
#endif
}
__device__ __forceinline__ float fast_rcp(float x) {
#if __has_builtin(__builtin_amdgcn_rcpf)
  return __builtin_amdgcn_rcpf(x);
#else
  float r; asm("v_rcp_f32 %0, %1\n\ts_nop 1" : "=v"(r) : "v"(x)); return r;
#endif
}

#define MFMA(a, b, c) __builtin_amdgcn_mfma_f32_16x16x32_bf16((a), (b), (c), 0, 0, 0)

// ---------------------------------------------------------------------------
// proj_gemm v2 — UNCHANGED from round 5/6 (est ~24 us; isolates attn delta).
// ---------------------------------------------------------------------------
__global__ __launch_bounds__(256) void proj_gemm(
    const float* __restrict__ h_t, const float* __restrict__ srcp,
    const float* __restrict__ Wa, float* __restrict__ C)
{
  const int z = blockIdx.z;
  const float* __restrict__ A = z ? srcp : h_t;
  const int mbase = blockIdx.x * 64;
  const int nbase = blockIdx.y * 64;

  __shared__ bf16_t Ah[64][72];
  __shared__ bf16_t Al[64][72];
  __shared__ bf16_t Bh[64][72];   // transposed: Bh[n][k]
  __shared__ bf16_t Bl[64][72];

  const int tid  = threadIdx.x;
  const int lane = tid & 63;
  const int wv   = tid >> 6;          // 0..3
  const int wm   = (wv & 1) * 32;
  const int wn   = (wv >> 1) * 32;
  const int l15  = lane & 15;
  const int qd   = lane >> 4;

  const int arow = tid >> 2;
  const int akc  = (tid & 3) * 16;
  const int bn = tid & 63;
  const int bkg = (tid >> 6) * 16;

  const float* Aptr = A + (size_t)(mbase + arow) * HID + akc;
  const float* Bptr = Wa + (size_t)(z * HID + bkg) * ATT + nbase + bn;

  f32x4 acc00 = {0.f, 0.f, 0.f, 0.f};
  f32x4 acc01 = acc00, acc10 = acc00, acc11 = acc00;

  for (int kb = 0; kb < HID; kb += 64) {
    if (kb) __syncthreads();

    {
      float4 a0 = *(const float4*)(Aptr + kb);
      float4 a1 = *(const float4*)(Aptr + kb + 4);
      float4 a2 = *(const float4*)(Aptr + kb + 8);
      float4 a3 = *(const float4*)(Aptr + kb + 12);
      float av[16] = {a0.x, a0.y, a0.z, a0.w, a1.x, a1.y, a1.z, a1.w,
                      a2.x, a2.y, a2.z, a2.w, a3.x, a3.y, a3.z, a3.w};
      bf16x8 hi0, hi1, lo0, lo1;
#pragma unroll
      for (int j = 0; j < 8; ++j) {
        bf16_t h = (bf16_t)av[j];
        hi0[j] = h;
        lo0[j] = (bf16_t)(av[j] - (float)h);
        bf16_t h2 = (bf16_t)av[j + 8];
        hi1[j] = h2;
        lo1[j] = (bf16_t)(av[j + 8] - (float)h2);
      }
      *(bf16x8*)&Ah[arow][akc]     = hi0;
      *(bf16x8*)&Ah[arow][akc + 8] = hi1;
      *(bf16x8*)&Al[arow][akc]     = lo0;
      *(bf16x8*)&Al[arow][akc + 8] = lo1;
    }

    {
      const float* bp = Bptr + (size_t)kb * ATT;
      float bv[16];
#pragma unroll
      for (int j = 0; j < 16; ++j) bv[j] = bp[(size_t)j * ATT];
      bf16x8 hi0, hi1, lo0, lo1;
#pragma unroll
      for (int j = 0; j < 8; ++j) {
        bf16_t h = (bf16_t)bv[j];
        hi0[j] = h;
        lo0[j] = (bf16_t)(bv[j] - (float)h);
        bf16_t h2 = (bf16_t)bv[j + 8];
        hi1[j] = h2;
        lo1[j] = (bf16_t)(bv[j + 8] - (float)h2);
      }
      *(bf16x8*)&Bh[bn][bkg]     = hi0;
      *(bf16x8*)&Bh[bn][bkg + 8] = hi1;
      *(bf16x8*)&Bl[bn][bkg]     = lo0;
      *(bf16x8*)&Bl[bn][bkg + 8] = lo1;
    }
    __syncthreads();

#pragma unroll
    for (int h = 0; h < 2; ++h) {
      const int kh = h * 32 + qd * 8;
      bf16x8 ah0 = *(const bf16x8*)&Ah[wm + l15][kh];
      bf16x8 ah1 = *(const bf16x8*)&Ah[wm + 16 + l15][kh];
      bf16x8 al0 = *(const bf16x8*)&Al[wm + l15][kh];
      bf16x8 al1 = *(const bf16x8*)&Al[wm + 16 + l15][kh];
      bf16x8 bh0 = *(const bf16x8*)&Bh[wn + l15][kh];
      bf16x8 bh1 = *(const bf16x8*)&Bh[wn + 16 + l15][kh];
      bf16x8 bl0 = *(const bf16x8*)&Bl[wn + l15][kh];
      bf16x8 bl1 = *(const bf16x8*)&Bl[wn + 16 + l15][kh];

      acc00 = MFMA(ah0, bh0, acc00);
      acc01 = MFMA(ah0, bh1, acc01);
      acc10 = MFMA(ah1, bh0, acc10);
      acc11 = MFMA(ah1, bh1, acc11);
      acc00 = MFMA(al0, bh0, acc00);
      acc01 = MFMA(al0, bh1, acc01);
      acc10 = MFMA(al1, bh0, acc10);
      acc11 = MFMA(al1, bh1, acc11);
      acc00 = MFMA(ah0, bl0, acc00);
      acc01 = MFMA(ah0, bl1, acc01);
      acc10 = MFMA(ah1, bl0, acc10);
      acc11 = MFMA(ah1, bl1, acc11);
    }
  }

  float* Cz = C + (size_t)z * (MROWS * ATT);
#pragma unroll
  for (int r = 0; r < 4; ++r) {
    int row0 = mbase + wm + qd * 4 + r;
    int row1 = row0 + 16;
    int col0 = nbase + wn + l15;
    Cz[(size_t)row0 * ATT + col0]      = acc00[r];
    Cz[(size_t)row0 * ATT + col0 + 16] = acc01[r];
    Cz[(size_t)row1 * ATT + col0]      = acc10[r];
    Cz[(size_t)row1 * ATT + col0 + 16] = acc11[r];
  }
}

// ---------------------------------------------------------------------------
// attn_fused v4: transcendental-issue diet.
//   exp2(SC*(h+s)) = eH[t][j] * ex[j]  -> ONE v_exp per (s,j) for ALL 4 t's
//   paired reciprocals: 1/y0 = rcp(y0*y1)*y1, 1/y1 = rcp(y0*y1)*y0
// Trans ops/element: 2.0 -> 0.75. Block = (4 targets, b), 512 thr, 8 waves;
// wave w handles s-rows w*8..w*8+7.
// ---------------------------------------------------------------------------
__global__ __launch_bounds__(512) void attn_fused(
    const float* __restrict__ ws, const float* __restrict__ srcp,
    const float* __restrict__ Va, float* __restrict__ out)
{
  const float* __restrict__ h_part = ws;
  const float* __restrict__ s_part = ws + (size_t)TGT * BATCH * ATT;
  const float SC = 2.8853900817779268f;   // 2*log2(e)

  const int t0   = blockIdx.x * 4;
  const int b    = blockIdx.y;
  const int tid  = threadIdx.x;
  const int lane = tid & 63;
  const int wv   = tid >> 6;              // 0..7

  __shared__ float scoreLds[4][64];
  __shared__ float attnLds[4][64];

  const int abase = lane * 8;
  float va[8], eH[4][8];
  *(float4*)&va[0] = *(const float4*)(Va + abase);
  *(float4*)&va[4] = *(const float4*)(Va + abase + 4);

  float vsum = 0.f;
#pragma unroll
  for (int j = 0; j < 8; ++j) vsum += va[j];
#pragma unroll
  for (int off = 32; off; off >>= 1) vsum += __shfl_xor(vsum, off);

#pragma unroll
  for (int t = 0; t < 4; ++t) {
    const float* hp = h_part + ((size_t)(t0 + t) * BATCH + b) * ATT + abase;
    float4 h0 = *(const float4*)hp;
    float4 h1 = *(const float4*)(hp + 4);
    float hv[8] = {h0.x, h0.y, h0.z, h0.w, h1.x, h1.y, h1.z, h1.w};
#pragma unroll
    for (int j = 0; j < 8; ++j) eH[t][j] = fast_exp2(hv[j] * SC);
  }

  // ---- scores: 8 s-rows per wave ----
#pragma unroll 2
  for (int i = 0; i < 8; ++i) {
    const int s = wv * 8 + i;
    const float* sp = s_part + ((size_t)s * BATCH + b) * ATT + abase;
    float4 s0 = *(const float4*)sp;
    float4 s1 = *(const float4*)(sp + 4);
    float sv[8] = {s0.x, s0.y, s0.z, s0.w, s1.x, s1.y, s1.z, s1.w};
    float ex[8];
#pragma unroll
    for (int j = 0; j < 8; ++j) ex[j] = fast_exp2(sv[j] * SC);

    float q0 = 0.f, q1 = 0.f, q2 = 0.f, q3 = 0.f;
#pragma unroll
    for (int j = 0; j < 8; ++j) {
      float e = ex[j];
      float vj = va[j];
      float y0 = fmaf(e, eH[0][j], 1.0f);
      float y1 = fmaf(e, eH[1][j], 1.0f);
      float y2 = fmaf(e, eH[2][j], 1.0f);
      float y3 = fmaf(e, eH[3][j], 1.0f);
      float r01 = fast_rcp(y0 * y1);
      float r23 = fast_rcp(y2 * y3);
      q0 = fmaf(vj * y1, r01, q0);
      q1 = fmaf(vj * y0, r01, q1);
      q2 = fmaf(vj * y3, r23, q2);
      q3 = fmaf(vj * y2, r23, q3);
    }
#pragma unroll
    for (int off = 32; off; off >>= 1) {
      q0 += __shfl_xor(q0, off);
      q1 += __shfl_xor(q1, off);
      q2 += __shfl_xor(q2, off);
      q3 += __shfl_xor(q3, off);
    }
    if (lane == 0) {
      scoreLds[0][s] = vsum - 2.0f * q0;
      scoreLds[1][s] = vsum - 2.0f * q1;
      scoreLds[2][s] = vsum - 2.0f * q2;
      scoreLds[3][s] = vsum - 2.0f * q3;
    }
  }
  __syncthreads();

  // ---- softmax over s: waves 0..3 handle t = wv, lane = s ----
  if (wv < 4) {
    float sc = scoreLds[wv][lane];
    float m = sc;
#pragma unroll
    for (int off = 32; off; off >>= 1) m = fmaxf(m, __shfl_xor(m, off));
    float e = fast_exp2((sc - m) * 1.4426950408889634f);
    float ssum = e;
#pragma unroll
    for (int off = 32; off; off >>= 1) ssum += __shfl_xor(ssum, off);
    attnLds[wv][lane] = e * fast_rcp(ssum);
  }
  __syncthreads();

  // ---- context: thread h = tid covers one of 512 hidden dims ----
  {
    float c0 = 0.f, c1 = 0.f, c2 = 0.f, c3 = 0.f;
    const float* sb = srcp + (size_t)b * HID + tid;
#pragma unroll 8
    for (int s = 0; s < SRCN; ++s) {
      float sv = sb[(size_t)s * BATCH * HID];
      c0 = fmaf(attnLds[0][s], sv, c0);
      c1 = fmaf(attnLds[1][s], sv, c1);
      c2 = fmaf(attnLds[2][s], sv, c2);
      c3 = fmaf(attnLds[3][s], sv, c3);
    }
    out[((size_t)(t0 + 0) * BATCH + b) * HID + tid] = c0;
    out[((size_t)(t0 + 1) * BATCH + b) * HID + tid] = c1;
    out[((size_t)(t0 + 2) * BATCH + b) * HID + tid] = c2;
    out[((size_t)(t0 + 3) * BATCH + b) * HID + tid] = c3;
  }
}

extern "C" void kernel_launch(void* const* d_in, const int* in_sizes, int n_in,
                              void* d_out, int out_size, void* d_ws, size_t ws_size,
                              hipStream_t stream) {
  const float* h_t = (const float*)d_in[0];   // (64,32,512)
  const float* src = (const float*)d_in[1];   // (64,32,512)
  const float* Wa  = (const float*)d_in[2];   // (1024,512)
  const float* Va  = (const float*)d_in[3];   // (512,)
  float* out = (float*)d_out;                 // (64,32,512)
  float* C   = (float*)d_ws;                  // 8 MB: h_part + s_part fp32 [z][2048][512]

  proj_gemm<<<dim3(32, 8, 2), 256, 0, stream>>>(h_t, src, Wa, C);
  attn_fused<<<dim3(16, 32), 512, 0, stream>>>(C, src, Va, out);
}